// Round 17
// baseline (43.983 us; speedup 1.0000x reference)
//
#include <hip/hip_runtime.h>
#include <hip/hip_bf16.h>
#include <math.h>

#define B_  8
#define S_  2048
#define E_  768
#define I_  64

typedef __attribute__((ext_vector_type(4)))  float f32x4;
typedef __attribute__((ext_vector_type(16))) float f32x16;
typedef __attribute__((ext_vector_type(8)))  short short8;
typedef __attribute__((ext_vector_type(4)))  short short4v;

// fp32 -> bf16 (RNE), raw 16-bit pattern
static __device__ __forceinline__ short bf16_of(float x) {
    unsigned u = __builtin_bit_cast(unsigned, x);
    u += 0x7fffu + ((u >> 16) & 1u);
    return (short)(u >> 16);
}

// packed pair conversion (compiler may fuse to v_cvt_pk_bf16_f32)
static __device__ __forceinline__ unsigned pk2(float lo, float hi) {
    __hip_bfloat162 h = __float22bfloat162_rn(float2{lo, hi});
    unsigned u; __builtin_memcpy(&u, &h, 4);
    return u;
}
static __device__ __forceinline__ short8 pk8(f32x4 a, f32x4 b) {
    union { unsigned u[4]; short8 s; } r;
    r.u[0] = pk2(a[0], a[1]); r.u[1] = pk2(a[2], a[3]);
    r.u[2] = pk2(b[0], b[1]); r.u[3] = pk2(b[2], b[3]);
    return r.s;
}

// async global->LDS, 16B per lane; dest wave-uniform base + lane*16
typedef __attribute__((address_space(1))) const void gv_t;
typedef __attribute__((address_space(3))) void lv_t;
static __device__ __forceinline__ void gload16(const void* g, void* l) {
    __builtin_amdgcn_global_load_lds((gv_t*)g, (lv_t*)l, 16, 0, 0);
}

// raw barrier + counted waits
#define BARRIER()   asm volatile("s_barrier" ::: "memory")
#define VMCNT(n)    asm volatile("s_waitcnt vmcnt(" #n ")" ::: "memory")

// ---------------- kernel 1: weight/bias conversion (fold qscale into Wq,bq) ----
__global__ void wconv(const float* __restrict__ Wq, const float* __restrict__ bq,
                      const float* __restrict__ Wk, const float* __restrict__ bk,
                      const float* __restrict__ Wv, const float* __restrict__ bv,
                      short* __restrict__ Wb, float* __restrict__ bb, float qscale) {
    int r = blockIdx.x;           // 0..191
    const float* src; const float* bsrc; float sc;
    if (r < 64)       { src = Wq + r * E_;         bsrc = bq + r;         sc = qscale; }
    else if (r < 128) { src = Wk + (r - 64) * E_;  bsrc = bk + (r - 64);  sc = 1.0f; }
    else              { src = Wv + (r - 128) * E_; bsrc = bv + (r - 128); sc = 1.0f; }
    for (int j = threadIdx.x; j < E_; j += blockDim.x)
        Wb[r * E_ + j] = bf16_of(src[j] * sc);
    if (threadIdx.x == 0) bb[r] = bsrc[0] * sc;
}

// ---------------- kernel 2: QKV projection, counted-vmcnt dbuf GEMM -----------
// (unchanged, verified: 512 blocks x 256 thr; BM=32, Kstep=64)
__global__ __launch_bounds__(256) void qkv_proj(
    const float* __restrict__ emb, const short* __restrict__ Wb,
    const float* __restrict__ bb,
    short* __restrict__ qb, short* __restrict__ kb, short* __restrict__ vT)
{
    __shared__ float Af[2][32][64];     // 16 KB, XOR-swizzled 16B slots (^row&15)
    __shared__ short Wf[2][192][64];    // 48 KB, XOR-swizzled 16B slots (^row&7)

    const int tid = threadIdx.x, w = tid >> 6, l = tid & 63;
    const int lr = l & 15, rg = l >> 4;
    const int sm = w & 1, sc = w >> 1;
    const int m0 = blockIdx.x * 32;

    f32x4 acc[6];
#pragma unroll
    for (int t = 0; t < 6; ++t) acc[t] = (f32x4){0.f, 0.f, 0.f, 0.f};

    auto STAGE = [&](int ks, int d) {
        char* ab = (char*)&Af[d][0][0] + w * 2048;
#pragma unroll
        for (int i = 0; i < 2; ++i) {
            int r = w * 8 + i * 4 + (l >> 4);
            const float* src = emb + (size_t)(m0 + r) * E_ + ks * 64 + (((l & 15) ^ (r & 15)) << 2);
            gload16(src, ab + i * 1024);
        }
        char* wb2 = (char*)&Wf[d][0][0] + w * 6144;
#pragma unroll
        for (int i = 0; i < 6; ++i) {
            int r = w * 48 + i * 8 + (l >> 3);
            const short* src = Wb + (size_t)r * E_ + ks * 64 + (((l & 7) ^ (r & 7)) << 3);
            gload16(src, wb2 + i * 1024);
        }
    };

    STAGE(0, 0);
    STAGE(1, 1);

    for (int ks = 0; ks < 12; ++ks) {
        const int cur = ks & 1;
        if (ks == 11) { VMCNT(0); } else { VMCNT(8); }
        BARRIER();
#pragma unroll
        for (int h = 0; h < 2; ++h) {
            const int r = sm * 16 + lr;
            const int s0 = (h * 8 + rg * 2) ^ lr;
            const int s1 = (h * 8 + rg * 2 + 1) ^ lr;
            f32x4 a0 = *(const f32x4*)&Af[cur][r][s0 * 4];
            f32x4 a1 = *(const f32x4*)&Af[cur][r][s1 * 4];
            short8 af = pk8(a0, a1);
#pragma unroll
            for (int tt = 0; tt < 6; ++tt) {
                int rw = (sc * 6 + tt) * 16 + lr;
                short8 wf = *(const short8*)&Wf[cur][rw][((h * 4 + rg) ^ (lr & 7)) << 3];
                acc[tt] = __builtin_amdgcn_mfma_f32_16x16x32_bf16(af, wf, acc[tt], 0, 0, 0);
            }
        }
        BARRIER();
        if (ks + 2 < 12) STAGE(ks + 2, cur);
    }

#pragma unroll
    for (int tt = 0; tt < 6; ++tt) {
        int col = sc * 96 + tt * 16 + lr;
        float bias = bb[col];
        int row = m0 + sm * 16 + rg * 4;
        if (col < 64) {
#pragma unroll
            for (int j = 0; j < 4; ++j)
                qb[(size_t)(row + j) * 64 + col] = bf16_of(acc[tt][j] + bias);
        } else if (col < 128) {
#pragma unroll
            for (int j = 0; j < 4; ++j)
                kb[(size_t)(row + j) * 64 + (col - 64)] = bf16_of(acc[tt][j] + bias);
        } else {
            short4v pv;
#pragma unroll
            for (int j = 0; j < 4; ++j) pv[j] = bf16_of(acc[tt][j] + bias);
            int b = row >> 11, s = row & 2047;
            *(short4v*)&vT[((size_t)b * 64 + (col - 128)) * S_ + s] = pv;
        }
    }
}

// ------- kernel 3: flash attention, 32x32 swapped QK^T + 16x16 PV -------------
// 256 blocks x 512 thr: batch=bid&7 (XCD-affine), qt=bid>>3 (64 q-rows).
// 8 waves = 2 rowgroups(g: 32 q-rows) x 4 KV-quarters(c: KT=64, 8 iters).
// QK via mfma_32x32x16 (A=K-frag from LDS, B=Q in regs): K/V LDS reads serve
// 32 q-rows each -> ~1.4x fewer LDS bytes per q*k than r11's 16-row waves.
// P lane-local (q=lane&31); per kt-half: 4 b64 writes -> padded [32][12] pbuf
// (96B rows spread banks), 2 b128 reads as 16x16 A-frags. PV = r11 V path.
// LDS 152 KB = Kb 64 + Vb 64 + pbuf 24; 1 block/CU, 2 waves/SIMD (as r11).
__global__ __launch_bounds__(512) void flash_attn(
    const short* __restrict__ qb, const short* __restrict__ kb,
    const short* __restrict__ vT, float* __restrict__ out)
{
    __shared__ __align__(16) char smem[155648];
    short (*Kb)[2][64][64] = (short(*)[2][64][64])(smem);            // 64 KB [c][d]
    short (*Vb)[2][64][64] = (short(*)[2][64][64])(smem + 65536);    // 64 KB [c][d]
    uint2 (*pbuf)[32][12]  = (uint2(*)[32][12])(smem + 131072);      // 24 KB [w][q][slot]
    // epilogue aliases (dead Kb after final barrier): mp 6x8KB, rsp 6x128B

    const int tid = threadIdx.x, w = tid >> 6, l = tid & 63;
    const int lr = l & 15, rg = l >> 4 & 3, h = l >> 5, q32 = l & 31;
    const int g = w & 1, c = w >> 1;
    const int batch = blockIdx.x & 7;
    const int qt = blockIdx.x >> 3;            // 0..31
    const int qloc0 = qt * 64 + g * 32;        // this wave's 32 q-rows

    const short* kbB = kb + (size_t)batch * S_ * 64;
    const short* vTB = vT + (size_t)batch * 64 * S_;

    const int swsrc = ((l & 7) ^ (l >> 3)) << 3;   // source slot pre-swizzle
    auto STAGE = [&](int ks2, int d) {
        const int k0 = c * 512 + ks2 * 64;
        char* kd = (char*)&Kb[c][d][0][0] + g * 4096;
        char* vd = (char*)&Vb[c][d][0][0] + g * 4096;
#pragma unroll
        for (int i = 0; i < 4; ++i) {
            const int r = g * 32 + i * 8 + (l >> 3);
            gload16(kbB + (size_t)(k0 + r) * 64 + swsrc, kd + i * 1024);
            gload16(vTB + (size_t)r * S_ + k0 + swsrc, vd + i * 1024);
        }
    };

    // Q as 32x32 B-frags: B[col=q=lane&31][k-deep d = seg*16 + h*8 + reg]
    short8 aq32[4];
#pragma unroll
    for (int seg = 0; seg < 4; ++seg)
        aq32[seg] = *(const short8*)(qb + (size_t)(batch * S_ + qloc0 + q32) * 64 + seg * 16 + h * 8);

    f32x4 acc[2][4];
    float rs = 0.f;
#pragma unroll
    for (int qt2 = 0; qt2 < 2; ++qt2)
#pragma unroll
        for (int n = 0; n < 4; ++n) acc[qt2][n] = (f32x4){0.f, 0.f, 0.f, 0.f};

    // pbuf addresses (loop-invariant): write slots per rq, read slot pair
    const int psw = 2 * ((q32 >> 2) & 3);
    uint2* pwr[4];
#pragma unroll
    for (int rq = 0; rq < 4; ++rq) pwr[rq] = &pbuf[w][q32][((2 * rq + h) + psw) % 12];
    const int psr = (2 * rg + 2 * ((lr >> 2) & 3)) % 12;
    const uint2* prd0 = &pbuf[w][lr][psr];
    const uint2* prd1 = &pbuf[w][16 + lr][psr];

    STAGE(0, 0);
    STAGE(1, 1);

    for (int ks = 0; ks < 8; ++ks) {
        const int cur = ks & 1;
        if (ks == 7) { VMCNT(0); } else { VMCNT(8); }   // 8 = next tile's loads
        BARRIER();

#pragma unroll
        for (int kt = 0; kt < 2; ++kt) {
            // ---- scores, SWAPPED 32x32: D[k][q] = mfma(K-frag, Q-frag) ----
            f32x16 z = (f32x16)(0.f);
#pragma unroll
            for (int seg = 0; seg < 4; ++seg) {
                short8 kf = *(const short8*)&Kb[c][cur][kt * 32 + q32][(((seg * 2 + h) ^ (q32 & 7)) << 3)];
                z = __builtin_amdgcn_mfma_f32_32x32x16_bf16(kf, aq32[seg], z, 0, 0, 0);
            }
            // ---- P = exp2; lane-local row-sum; quad-packed b64 writes ----
#pragma unroll
            for (int rq = 0; rq < 4; ++rq) {
                float p0 = __builtin_amdgcn_exp2f(z[rq * 4 + 0]);
                float p1 = __builtin_amdgcn_exp2f(z[rq * 4 + 1]);
                float p2 = __builtin_amdgcn_exp2f(z[rq * 4 + 2]);
                float p3 = __builtin_amdgcn_exp2f(z[rq * 4 + 3]);
                rs += (p0 + p1) + (p2 + p3);
                *pwr[rq] = uint2{pk2(p0, p1), pk2(p2, p3)};
            }
            // ---- read as 16x16 A-frags (k-half = kt) ----
            short8 pa0 = *(const short8*)prd0;
            short8 pa1 = *(const short8*)prd1;
            // ---- PV (r11 V path; V frags serve both q-tiles) ----
#pragma unroll
            for (int n = 0; n < 4; ++n) {
                short8 vf = *(const short8*)&Vb[c][cur][n * 16 + lr][(((kt * 4 + rg) ^ (lr & 7)) << 3)];
                acc[0][n] = __builtin_amdgcn_mfma_f32_16x16x32_bf16(pa0, vf, acc[0][n], 0, 0, 0);
                acc[1][n] = __builtin_amdgcn_mfma_f32_16x16x32_bf16(pa1, vf, acc[1][n], 0, 0, 0);
            }
        }

        BARRIER();
        if (ks + 2 < 8) STAGE(ks + 2, cur);
    }

    // ---- finish chunk row-sum: halves h=0/1 hold disjoint k subsets ----
    rs += __shfl_xor(rs, 32, 64);     // rs = full chunk sum for q = q32

    // ---- 4-way chunk merge via dead Kb LDS ----
    if (c != 0) {
        const int widx = (c - 1) * 2 + g;                 // 0..5
        float* mp  = (float*)(smem + widx * 8192);
        float* rsp = (float*)(smem + 49152 + widx * 128);
#pragma unroll
        for (int qt2 = 0; qt2 < 2; ++qt2)
#pragma unroll
            for (int n = 0; n < 4; ++n)
#pragma unroll
                for (int j = 0; j < 4; ++j)
                    mp[l * 32 + qt2 * 16 + n * 4 + j] = acc[qt2][n][j];
        if (l < 32) rsp[l] = rs;
    }
    __syncthreads();
    if (c == 0) {
#pragma unroll
        for (int qt2 = 0; qt2 < 2; ++qt2) {
#pragma unroll
            for (int j = 0; j < 4; ++j) {
                const int qj = qt2 * 16 + rg * 4 + j;     // q-local 0..31
                float tot = __shfl(rs, qj, 64);
#pragma unroll
                for (int cc = 1; cc < 4; ++cc)
                    tot += ((const float*)(smem + 49152 + ((cc - 1) * 2 + g) * 128))[qj];
                float inv = 1.0f / tot;
                float* orow = out + (size_t)(batch * S_ + qloc0 + qj) * 64;
#pragma unroll
                for (int n = 0; n < 4; ++n) {
                    float v = acc[qt2][n][j];
#pragma unroll
                    for (int cc = 1; cc < 4; ++cc)
                        v += ((const float*)(smem + ((cc - 1) * 2 + g) * 8192))[l * 32 + qt2 * 16 + n * 4 + j];
                    orow[n * 16 + lr] = v * inv;
                }
            }
        }
    }
}

extern "C" void kernel_launch(void* const* d_in, const int* in_sizes, int n_in,
                              void* d_out, int out_size, void* d_ws, size_t ws_size,
                              hipStream_t stream) {
    const float* emb = (const float*)d_in[0];
    const float* Wq  = (const float*)d_in[1];
    const float* bq  = (const float*)d_in[2];
    const float* Wk  = (const float*)d_in[3];
    const float* bk  = (const float*)d_in[4];
    const float* Wv  = (const float*)d_in[5];
    const float* bv  = (const float*)d_in[6];
    float* out = (float*)d_out;

    char* ws = (char*)d_ws;
    short* Wb  = (short*)(ws + 0);                          // 192*768*2 = 294912
    float* bb  = (float*)(ws + 294912);                     // 192*4 (pad to 768)
    short* qb  = (short*)(ws + 295680);                     // 2 MB
    short* kb  = (short*)(ws + 295680 + 2097152);           // 2 MB
    short* vT  = (short*)(ws + 295680 + 2 * 2097152);       // 2 MB

    const float qscale = 1.4426950408889634f / sqrtf((float)E_);

    hipLaunchKernelGGL(wconv, dim3(192), dim3(256), 0, stream,
                       Wq, bq, Wk, bk, Wv, bv, Wb, bb, qscale);
    hipLaunchKernelGGL(qkv_proj, dim3(512), dim3(256), 0, stream,
                       emb, Wb, bb, qb, kb, vT);
    hipLaunchKernelGGL(flash_attn, dim3(256), dim3(512), 0, stream,
                       qb, kb, vT, out);
}

// Round 18
// 41.233 us; speedup vs baseline: 1.0667x; 1.0667x over previous
//
#include <hip/hip_runtime.h>
#include <hip/hip_bf16.h>
#include <math.h>

#define B_  8
#define S_  2048
#define E_  768
#define I_  64

typedef __attribute__((ext_vector_type(4))) float f32x4;
typedef __attribute__((ext_vector_type(8))) short short8;
typedef __attribute__((ext_vector_type(4))) short short4v;

// fp32 -> bf16 (RNE), raw 16-bit pattern (epilogue scalar use)
static __device__ __forceinline__ short bf16_of(float x) {
    unsigned u = __builtin_bit_cast(unsigned, x);
    u += 0x7fffu + ((u >> 16) & 1u);
    return (short)(u >> 16);
}

// packed pair conversion via HW v_cvt_pk_bf16_f32 (compiler-fused pair cast)
static __device__ __forceinline__ unsigned pk2(float lo, float hi) {
    __hip_bfloat162 h = __float22bfloat162_rn(float2{lo, hi});
    unsigned u; __builtin_memcpy(&u, &h, 4);
    return u;
}
static __device__ __forceinline__ short8 pk8(f32x4 a, f32x4 b) {
    union { unsigned u[4]; short8 s; } r;
    r.u[0] = pk2(a[0], a[1]); r.u[1] = pk2(a[2], a[3]);
    r.u[2] = pk2(b[0], b[1]); r.u[3] = pk2(b[2], b[3]);
    return r.s;
}

// async global->LDS, 16B per lane; dest wave-uniform base + lane*16
typedef __attribute__((address_space(1))) const void gv_t;
typedef __attribute__((address_space(3))) void lv_t;
static __device__ __forceinline__ void gload16(const void* g, void* l) {
    __builtin_amdgcn_global_load_lds((gv_t*)g, (lv_t*)l, 16, 0, 0);
}

// raw barrier + counted waits (asm so no implicit vmcnt(0) drain, no reordering)
#define BARRIER()   asm volatile("s_barrier" ::: "memory")
#define VMCNT(n)    asm volatile("s_waitcnt vmcnt(" #n ")" ::: "memory")

// ---------------- kernel 1: weight/bias conversion (fold qscale into Wq,bq) ----
__global__ void wconv(const float* __restrict__ Wq, const float* __restrict__ bq,
                      const float* __restrict__ Wk, const float* __restrict__ bk,
                      const float* __restrict__ Wv, const float* __restrict__ bv,
                      short* __restrict__ Wb, float* __restrict__ bb, float qscale) {
    int r = blockIdx.x;           // 0..191
    const float* src; const float* bsrc; float sc;
    if (r < 64)       { src = Wq + r * E_;         bsrc = bq + r;         sc = qscale; }
    else if (r < 128) { src = Wk + (r - 64) * E_;  bsrc = bk + (r - 64);  sc = 1.0f; }
    else              { src = Wv + (r - 128) * E_; bsrc = bv + (r - 128); sc = 1.0f; }
    for (int j = threadIdx.x; j < E_; j += blockDim.x)
        Wb[r * E_ + j] = bf16_of(src[j] * sc);
    if (threadIdx.x == 0) bb[r] = bsrc[0] * sc;
}

// ---------------- kernel 2: QKV projection, counted-vmcnt dbuf GEMM -----------
// 512 blocks x 256 thr; BM=32, N=192, Kstep=64, 12 iters; 64KB LDS.
__global__ __launch_bounds__(256) void qkv_proj(
    const float* __restrict__ emb, const short* __restrict__ Wb,
    const float* __restrict__ bb,
    short* __restrict__ qb, short* __restrict__ kb, short* __restrict__ vT)
{
    __shared__ float Af[2][32][64];     // 16 KB, XOR-swizzled 16B slots (^row&15)
    __shared__ short Wf[2][192][64];    // 48 KB, XOR-swizzled 16B slots (^row&7)

    const int tid = threadIdx.x, w = tid >> 6, l = tid & 63;
    const int lr = l & 15, rg = l >> 4;
    const int sm = w & 1, sc = w >> 1;
    const int m0 = blockIdx.x * 32;

    f32x4 acc[6];
#pragma unroll
    for (int t = 0; t < 6; ++t) acc[t] = (f32x4){0.f, 0.f, 0.f, 0.f};

    auto STAGE = [&](int ks, int d) {
        char* ab = (char*)&Af[d][0][0] + w * 2048;
#pragma unroll
        for (int i = 0; i < 2; ++i) {
            int r = w * 8 + i * 4 + (l >> 4);
            const float* src = emb + (size_t)(m0 + r) * E_ + ks * 64 + (((l & 15) ^ (r & 15)) << 2);
            gload16(src, ab + i * 1024);
        }
        char* wb2 = (char*)&Wf[d][0][0] + w * 6144;
#pragma unroll
        for (int i = 0; i < 6; ++i) {
            int r = w * 48 + i * 8 + (l >> 3);
            const short* src = Wb + (size_t)r * E_ + ks * 64 + (((l & 7) ^ (r & 7)) << 3);
            gload16(src, wb2 + i * 1024);
        }
    };

    STAGE(0, 0);
    STAGE(1, 1);

    for (int ks = 0; ks < 12; ++ks) {
        const int cur = ks & 1;
        if (ks == 11) { VMCNT(0); } else { VMCNT(8); }   // 8 = next tile's loads
        BARRIER();
#pragma unroll
        for (int h = 0; h < 2; ++h) {
            const int r = sm * 16 + lr;                   // r&15 == lr
            const int s0 = (h * 8 + rg * 2) ^ lr;
            const int s1 = (h * 8 + rg * 2 + 1) ^ lr;
            f32x4 a0 = *(const f32x4*)&Af[cur][r][s0 * 4];
            f32x4 a1 = *(const f32x4*)&Af[cur][r][s1 * 4];
            short8 af = pk8(a0, a1);
#pragma unroll
            for (int tt = 0; tt < 6; ++tt) {
                int rw = (sc * 6 + tt) * 16 + lr;         // rw&7 == lr&7
                short8 wf = *(const short8*)&Wf[cur][rw][((h * 4 + rg) ^ (lr & 7)) << 3];
                acc[tt] = __builtin_amdgcn_mfma_f32_16x16x32_bf16(af, wf, acc[tt], 0, 0, 0);
            }
        }
        BARRIER();
        if (ks + 2 < 12) STAGE(ks + 2, cur);
    }

    // epilogue: bias + store q/k bf16 row-major, v transposed
#pragma unroll
    for (int tt = 0; tt < 6; ++tt) {
        int col = sc * 96 + tt * 16 + lr;    // 0..191
        float bias = bb[col];
        int row = m0 + sm * 16 + rg * 4;
        if (col < 64) {
#pragma unroll
            for (int j = 0; j < 4; ++j)
                qb[(size_t)(row + j) * 64 + col] = bf16_of(acc[tt][j] + bias);
        } else if (col < 128) {
#pragma unroll
            for (int j = 0; j < 4; ++j)
                kb[(size_t)(row + j) * 64 + (col - 64)] = bf16_of(acc[tt][j] + bias);
        } else {
            short4v pv;
#pragma unroll
            for (int j = 0; j < 4; ++j) pv[j] = bf16_of(acc[tt][j] + bias);
            int b = row >> 11, s = row & 2047;
            *(short4v*)&vT[((size_t)b * 64 + (col - 128)) * S_ + s] = pv;
        }
    }
}

// ------- kernel 3: flash attention, swapped-QK^T P-path, 2-way KV split -------
// 256 blocks x 512 thr: batch=bid&7 (XCD-affine), qt=bid>>3 (64 q-rows).
// wave w: g=w&3 (rowgroup, 16 rows), c=w>>2 (KV half, 16 steps).
// Swapped mfma(K,Q) => lane owns one q-row's P slice: P transpose is
// 4 ds_write_b64 + 2 ds_read_b128 (was 32 b16 writes); rs is a lane scalar.
// V staged via coalesced global_load_lds; swizzled LDS read = the transpose.
// LDS = 80KB exactly (merge buffers alias dead Kb) -> fits; 8 waves/CU.
__global__ __launch_bounds__(512) void flash_attn(
    const short* __restrict__ qb, const short* __restrict__ kb,
    const short* __restrict__ vT, float* __restrict__ out)
{
    __shared__ __align__(16) char smem[81920];
    // live during the K-loop:
    short (*Kb)[2][64][64] = (short(*)[2][64][64])(smem);            // 32 KB [c][d]
    short (*Vb)[2][64][64] = (short(*)[2][64][64])(smem + 32768);    // 32 KB [c][d]
    uint2 (*pbuf)[16][16]  = (uint2(*)[16][16]) (smem + 65536);      // 16 KB [w]: [q=lr][k-quad]
    // epilogue-only (aliases Kb; Kb is dead after final VMCNT(0)+BARRIER):
    float (*mbuf)[64][16]  = (float(*)[64][16])(smem);               // 16 KB [g]
    float (*rsb)[16]       = (float(*)[16])    (smem + 16384);       // 256 B [g]

    const int tid = threadIdx.x, w = tid >> 6, l = tid & 63;
    const int lr = l & 15, rg = l >> 4;
    const int g = w & 3, c = w >> 2;
    const int batch = blockIdx.x & 7;
    const int qt = blockIdx.x >> 3;        // 0..31
    const int qloc0 = qt * 64 + g * 16;

    const short* kbB = kb + (size_t)batch * S_ * 64;
    const short* vTB = vT + (size_t)batch * 64 * S_;

    const int swsrc = ((l & 7) ^ (l >> 3)) << 3;    // source slot pre-swizzle
    auto STAGE = [&](int ks, int d) {
        const int kt = c * 16 + ks;
        const int rl = g * 16 + (l >> 3);            // rl&7 == l>>3
        char* kd = (char*)&Kb[c][d][0][0] + g * 2048;
        gload16(kbB + (size_t)(kt * 64 + rl) * 64 + swsrc, kd);
        gload16(kbB + (size_t)(kt * 64 + rl + 8) * 64 + swsrc, kd + 1024);
        char* vd = (char*)&Vb[c][d][0][0] + g * 2048;
        gload16(vTB + (size_t)rl * S_ + kt * 64 + swsrc, vd);
        gload16(vTB + (size_t)(rl + 8) * S_ + kt * 64 + swsrc, vd + 1024);
    };

    short8 aq0 = *(const short8*)(qb + (size_t)(batch * S_ + qloc0 + lr) * 64 + rg * 8);
    short8 aq1 = *(const short8*)(qb + (size_t)(batch * S_ + qloc0 + lr) * 64 + 32 + rg * 8);

    f32x4 acc[4];
    float rs = 0.f;
#pragma unroll
    for (int n = 0; n < 4; ++n) acc[n] = (f32x4){0.f, 0.f, 0.f, 0.f};

    // iteration-invariant P-buffer addresses (uint2-slot XOR swizzle)
    const int Mu = (lr & 7) << 1;
    uint2* pwr[4];
#pragma unroll
    for (int t = 0; t < 4; ++t) pwr[t] = &pbuf[w][lr][(t * 4 + rg) ^ Mu];
    const uint2* prd0 = &pbuf[w][lr][(rg * 2) ^ Mu];
    const uint2* prd1 = &pbuf[w][lr][(8 + rg * 2) ^ Mu];

    STAGE(0, 0);
    STAGE(1, 1);

    for (int ks = 0; ks < 16; ++ks) {
        const int cur = ks & 1;
        if (ks == 15) { VMCNT(0); } else { VMCNT(4); }   // 4 = next tile's loads
        BARRIER();

        // ---- scores, SWAPPED: S^T[k][q] = mfma(K_frag, Q_frag) ----
        // lane (rg,lr): s2[t][j] = S[k = t*16+rg*4+j][q = lr]
        f32x4 s2[4];
#pragma unroll
        for (int t = 0; t < 4; ++t) {
            const int rk = t * 16 + lr;              // rk&7 == lr&7
            short8 kf0 = *(const short8*)&Kb[c][cur][rk][((0 * 4 + rg) ^ (lr & 7)) << 3];
            short8 kf1 = *(const short8*)&Kb[c][cur][rk][((1 * 4 + rg) ^ (lr & 7)) << 3];
            f32x4 z = (f32x4){0.f, 0.f, 0.f, 0.f};
            z = __builtin_amdgcn_mfma_f32_16x16x32_bf16(kf0, aq0, z, 0, 0, 0);
            s2[t] = __builtin_amdgcn_mfma_f32_16x16x32_bf16(kf1, aq1, z, 0, 0, 0);
        }
        // ---- P = exp2(s); lane-local row-sum; k-quad packed b64 stores ----
#pragma unroll
        for (int t = 0; t < 4; ++t) {
            float p0 = __builtin_amdgcn_exp2f(s2[t][0]);
            float p1 = __builtin_amdgcn_exp2f(s2[t][1]);
            float p2 = __builtin_amdgcn_exp2f(s2[t][2]);
            float p3 = __builtin_amdgcn_exp2f(s2[t][3]);
            rs += (p0 + p1) + (p2 + p3);
            *pwr[t] = uint2{pk2(p0, p1), pk2(p2, p3)};
        }
        short8 pa0 = *(const short8*)prd0;
        short8 pa1 = *(const short8*)prd1;
        // ---- PV ----
#pragma unroll
        for (int n = 0; n < 4; ++n) {
            const int ri = n * 16 + lr;
            short8 v0 = *(const short8*)&Vb[c][cur][ri][((0 * 4 + rg) ^ (lr & 7)) << 3];
            short8 v1 = *(const short8*)&Vb[c][cur][ri][((1 * 4 + rg) ^ (lr & 7)) << 3];
            acc[n] = __builtin_amdgcn_mfma_f32_16x16x32_bf16(pa0, v0, acc[n], 0, 0, 0);
            acc[n] = __builtin_amdgcn_mfma_f32_16x16x32_bf16(pa1, v1, acc[n], 0, 0, 0);
        }

        BARRIER();
        if (ks + 2 < 16) STAGE(ks + 2, cur);
    }

    // ---- finish row-sums (2-step: rg groups hold disjoint k subsets) ----
    rs += __shfl_xor(rs, 16, 64);
    rs += __shfl_xor(rs, 32, 64);     // now rs = full sum for q = lr (this chunk)

    // ---- merge the two KV halves through LDS (pure sums), normalize, store ----
    // (mbuf/rsb alias Kb: all Kb reads completed before the final BARRIER above)
    if (c == 1) {
#pragma unroll
        for (int n = 0; n < 4; ++n)
#pragma unroll
            for (int j = 0; j < 4; ++j) mbuf[g][l][n * 4 + j] = acc[n][j];
        if (l < 16) rsb[g][l] = rs;
    }
    __syncthreads();
    if (c == 0) {
        const int qrow = batch * S_ + qloc0 + rg * 4;
#pragma unroll
        for (int j = 0; j < 4; ++j) {
            const int qj = rg * 4 + j;
            float inv = 1.0f / (__shfl(rs, qj, 64) + rsb[g][qj]);
            float* orow = out + (size_t)(qrow + j) * 64;
#pragma unroll
            for (int n = 0; n < 4; ++n)
                orow[n * 16 + lr] = (acc[n][j] + mbuf[g][l][n * 4 + j]) * inv;
        }
    }
}

extern "C" void kernel_launch(void* const* d_in, const int* in_sizes, int n_in,
                              void* d_out, int out_size, void* d_ws, size_t ws_size,
                              hipStream_t stream) {
    const float* emb = (const float*)d_in[0];
    const float* Wq  = (const float*)d_in[1];
    const float* bq  = (const float*)d_in[2];
    const float* Wk  = (const float*)d_in[3];
    const float* bk  = (const float*)d_in[4];
    const float* Wv  = (const float*)d_in[5];
    const float* bv  = (const float*)d_in[6];
    float* out = (float*)d_out;

    char* ws = (char*)d_ws;
    short* Wb  = (short*)(ws + 0);                          // 192*768*2 = 294912
    float* bb  = (float*)(ws + 294912);                     // 192*4 (pad to 768)
    short* qb  = (short*)(ws + 295680);                     // 2 MB
    short* kb  = (short*)(ws + 295680 + 2097152);           // 2 MB
    short* vT  = (short*)(ws + 295680 + 2 * 2097152);       // 2 MB

    const float qscale = 1.4426950408889634f / sqrtf((float)E_);

    hipLaunchKernelGGL(wconv, dim3(192), dim3(256), 0, stream,
                       Wq, bq, Wk, bk, Wv, bv, Wb, bb, qscale);
    hipLaunchKernelGGL(qkv_proj, dim3(512), dim3(256), 0, stream,
                       emb, Wb, bb, qb, kb, vT);
    hipLaunchKernelGGL(flash_attn, dim3(256), dim3(512), 0, stream,
                       qb, kb, vT, out);
}